// Round 3
// baseline (170.691 us; speedup 1.0000x reference)
//
#include <hip/hip_runtime.h>

// RBF classifier: out = exp(-(||x-c||^2) * exp(-2*log_sigma)) @ W^T + b
// B=16384, D=784, C=2048, OUT=10. All fp32 in/out.
//
// R3: B operand (centres) pre-packed in MFMA B-fragment order and loaded
// direct global->VGPR (L2-resident, 3.4MB) -- halves LDS traffic vs R2
// (LDS was the co-dominant pipe at ~34 TB/s). A stays LDS-staged via
// global_load_lds w/ XOR swizzle. exp2-folded scale. K pad 784->832.

#define B_ROWS 16384
#define D_DIM  784
#define C_DIM  2048
#define NOUT   10
#define KPAD   832            // 26 x 32
#define NKC    26             // k-chunks of 32
#define NCG    128            // col-groups of 16
#define LOG2E  1.4426950408889634f

typedef __attribute__((ext_vector_type(8))) __bf16 bf16x8;
typedef __attribute__((ext_vector_type(4))) float  f32x4;
typedef __attribute__((ext_vector_type(4))) unsigned short ushort4v;

__device__ __forceinline__ unsigned short f2bf(float f) {
  union { float f; unsigned int u; } v; v.f = f;
  unsigned int u = v.u;
  return (unsigned short)((u + 0x7fffu + ((u >> 16) & 1u)) >> 16);  // RNE
}

// async global->LDS, 16B per lane. LDS dest = wave-uniform base + lane*16.
__device__ __forceinline__ void async16(const __bf16* g, __bf16* l) {
  __builtin_amdgcn_global_load_lds((const __attribute__((address_space(1))) void*)g,
                                   (__attribute__((address_space(3))) void*)l,
                                   16, 0, 0);
}

// --- x prep: fp32 row -> bf16 row (padded to KPAD zeros) + sum of squares.
// one WAVE per row; no LDS, no syncthreads.
__global__ __launch_bounds__(256) void prep_rows(const float* __restrict__ src,
                                                 unsigned short* __restrict__ dst,
                                                 float* __restrict__ sq) {
  const int row  = blockIdx.x * 4 + (threadIdx.x >> 6);
  const int lane = threadIdx.x & 63;
  const float* s = src + (size_t)row * D_DIM;
  unsigned short* d = dst + (size_t)row * KPAD;
  float acc = 0.f;
#pragma unroll
  for (int c = 0; c < 4; ++c) {
    const int ch = lane + c * 64;           // ushort4 chunk index, 208 total
    if (ch < 196) {
      const float4 v = ((const float4*)s)[ch];
      ushort4v o; o.x = f2bf(v.x); o.y = f2bf(v.y); o.z = f2bf(v.z); o.w = f2bf(v.w);
      *(ushort4v*)(d + ch * 4) = o;
      acc += v.x * v.x + v.y * v.y + v.z * v.z + v.w * v.w;
    } else if (ch < 208) {
      ushort4v z = {0, 0, 0, 0};
      *(ushort4v*)(d + ch * 4) = z;
    }
  }
#pragma unroll
  for (int off = 32; off > 0; off >>= 1) acc += __shfl_down(acc, off);
  if (lane == 0) sq[row] = acc;
}

// centres -> packed MFMA B-fragments. dst tile index t = kc*NCG+cg; lane
// (q,l16) holds B[k=kc*32+q*8+j][n=cg*16+l16], j=0..7 (16B). Coalesced write.
__global__ __launch_bounds__(256) void prep_cpack(const float* __restrict__ cen,
                                                  unsigned short* __restrict__ dst) {
  const int tile = blockIdx.x * 4 + (threadIdx.x >> 6);   // 0..NKC*NCG-1
  const int lane = threadIdx.x & 63;
  const int kc = tile >> 7;
  const int cg = tile & 127;
  const int c  = cg * 16 + (lane & 15);
  const int k  = kc * 32 + (lane >> 4) * 8;
  ushort4v o0 = {0, 0, 0, 0}, o1 = {0, 0, 0, 0};
  if (k + 8 <= D_DIM) {  // 784 % 8 == 0: chunks are fully in or fully pad
    const float4 v0 = *(const float4*)(cen + (size_t)c * D_DIM + k);
    const float4 v1 = *(const float4*)(cen + (size_t)c * D_DIM + k + 4);
    o0.x = f2bf(v0.x); o0.y = f2bf(v0.y); o0.z = f2bf(v0.z); o0.w = f2bf(v0.w);
    o1.x = f2bf(v1.x); o1.y = f2bf(v1.y); o1.z = f2bf(v1.z); o1.w = f2bf(v1.w);
  }
  unsigned short* p = dst + ((size_t)tile * 64 + lane) * 8;
  *(ushort4v*)p = o0;
  *(ushort4v*)(p + 4) = o1;
}

// centre squared norms only (wave per row).
__global__ __launch_bounds__(256) void prep_csq(const float* __restrict__ cen,
                                                float* __restrict__ sq) {
  const int row  = blockIdx.x * 4 + (threadIdx.x >> 6);
  const int lane = threadIdx.x & 63;
  const float* s = cen + (size_t)row * D_DIM;
  float acc = 0.f;
#pragma unroll
  for (int c = 0; c < 4; ++c) {
    const int ch = lane + c * 64;
    if (ch < 196) {
      const float4 v = ((const float4*)s)[ch];
      acc += v.x * v.x + v.y * v.y + v.z * v.z + v.w * v.w;
    }
  }
#pragma unroll
  for (int off = 32; off > 0; off >>= 1) acc += __shfl_down(acc, off);
  if (lane == 0) sq[row] = acc;
}

// fused tiny preps: out=bias | Wb bf16 (16,2048; rows 10..15 zero) | scale
// (pre-multiplied by log2(e) so epilogue uses exp2).
__global__ __launch_bounds__(256) void prep_misc(const float* __restrict__ ls,
                                                 const float* __restrict__ W,
                                                 const float* __restrict__ bias,
                                                 float* __restrict__ scale,
                                                 unsigned short* __restrict__ wb,
                                                 float* __restrict__ out) {
  const int i = blockIdx.x * 256 + threadIdx.x;
  if (i < B_ROWS * NOUT) out[i] = bias[i % NOUT];
  const int j = i - B_ROWS * NOUT;
  if (j >= 0 && j < 16 * C_DIM)
    wb[j] = ((j >> 11) < NOUT) ? f2bf(W[(j >> 11) * C_DIM + (j & 2047)]) : (unsigned short)0;
  const int k = j - 16 * C_DIM;
  if (k >= 0 && k < C_DIM) scale[k] = __expf(-2.f * ls[k]) * LOG2E;
}

// --- main fused kernel: 128x128 tile over (B,C), BK=64, 4 waves 2x2.
// A: LDS-staged (XOR swizzle). B: direct global->VGPR from packed frags (L2).
// LDS union: As(16K) overlaid by Ph(34K) for the epilogue.
__global__ __launch_bounds__(256, 4) void rbf_main(
    const __bf16* __restrict__ xb, const bf16x8* __restrict__ cbp,
    const __bf16* __restrict__ wb,
    const float* __restrict__ x2, const float* __restrict__ c2,
    const float* __restrict__ scale, float* __restrict__ out) {
  __shared__ char smem[34816];               // max(16384 A-stage, 34816 Ph)
  __bf16* As = (__bf16*)smem;                // 128 x 64
  __bf16* Ph = (__bf16*)smem;                // 128 x 136 (epilogue overlay)
  __shared__ float x2s[128], c2s[128], scs[128];

  const int tid  = threadIdx.x;
  const int w    = tid >> 6;
  const int lane = tid & 63;
  const int q    = lane >> 4;
  const int l16  = lane & 15;
  const int brow = blockIdx.x * 128;
  const int bcol = blockIdx.y * 128;

  if (tid < 128) x2s[tid] = x2[brow + tid];
  else { c2s[tid - 128] = c2[bcol + tid - 128]; scs[tid - 128] = scale[bcol + tid - 128]; }

  // A staging: thread t covers (row = r*32 + t/8, k-chunk = (t&7)^(row&7)).
  const int srow = tid >> 3;
  const int skc  = (tid & 7) ^ (srow & 7);
  const __bf16* gA = xb + (size_t)(brow + srow) * KPAD + skc * 8;
  __bf16* lA = As + w * 512;

  const int wr = (w >> 1) * 64;       // wave row offset
  const int wc = (w & 1) * 64;        // wave col offset
  const int cgb = (bcol >> 4) + (w & 1) * 4;  // wave's first col-group
  const int swz = l16 & 7;

  f32x4 acc[4][4] = {};

#pragma unroll 1
  for (int it = 0; it < NKC / 2; ++it) {
    const int k0 = it * 64;
#pragma unroll
    for (int r = 0; r < 4; ++r)
      async16(gA + (size_t)r * 32 * KPAD + k0, lA + r * 2048);
    __syncthreads();
#pragma unroll
    for (int ks = 0; ks < 2; ++ks) {
      const int kc = it * 2 + ks;
      bf16x8 af[4], bfr[4];
#pragma unroll
      for (int j = 0; j < 4; ++j)
        bfr[j] = cbp[((size_t)kc * NCG + cgb + j) * 64 + lane];
#pragma unroll
      for (int i = 0; i < 4; ++i)
        af[i] = *(const bf16x8*)&As[(wr + i * 16 + l16) * 64 + (((ks * 4 + q) ^ swz) << 3)];
#pragma unroll
      for (int i = 0; i < 4; ++i)
#pragma unroll
        for (int j = 0; j < 4; ++j)
          acc[i][j] = __builtin_amdgcn_mfma_f32_16x16x32_bf16(af[i], bfr[j], acc[i][j], 0, 0, 0);
    }
    __syncthreads();
  }

  // epilogue 1: d2 -> phi -> Ph (bf16). C/D layout: col=lane&15, row=q*4+r.
#pragma unroll
  for (int i = 0; i < 4; ++i) {
    float xv[4];
#pragma unroll
    for (int r = 0; r < 4; ++r) xv[r] = x2s[wr + i * 16 + q * 4 + r];
#pragma unroll
    for (int j = 0; j < 4; ++j) {
      const int cl = wc + j * 16 + l16;
      const float c2v = c2s[cl];
      const float sc = scs[cl];   // includes log2(e)
#pragma unroll
      for (int r = 0; r < 4; ++r) {
        const int rl = wr + i * 16 + q * 4 + r;
        const float d2 = fmaxf(fmaf(-2.f, acc[i][j][r], xv[r] + c2v), 0.f);
        Ph[rl * 136 + cl] = (__bf16)__builtin_exp2f(-d2 * sc);
      }
    }
  }
  __syncthreads();

  // epilogue 2: out_tile(128x10) = Ph(128x128) @ Wb(16-row slice)^T, K=128.
  f32x4 oacc[2] = {};
#pragma unroll
  for (int kk = 0; kk < 4; ++kk) {
    const bf16x8 bw = *(const bf16x8*)&wb[(size_t)l16 * C_DIM + bcol + kk * 32 + q * 8];
#pragma unroll
    for (int mi = 0; mi < 2; ++mi) {
      const bf16x8 ap = *(const bf16x8*)&Ph[(w * 32 + mi * 16 + l16) * 136 + kk * 32 + q * 8];
      oacc[mi] = __builtin_amdgcn_mfma_f32_16x16x32_bf16(ap, bw, oacc[mi], 0, 0, 0);
    }
  }
  if (l16 < NOUT) {
#pragma unroll
    for (int mi = 0; mi < 2; ++mi)
#pragma unroll
      for (int r = 0; r < 4; ++r) {
        const int grow = brow + w * 32 + mi * 16 + q * 4 + r;
        atomicAdd(&out[grow * NOUT + l16], oacc[mi][r]);
      }
  }
}

extern "C" void kernel_launch(void* const* d_in, const int* in_sizes, int n_in,
                              void* d_out, int out_size, void* d_ws, size_t ws_size,
                              hipStream_t stream) {
  const float* x    = (const float*)d_in[0];  // (16384,784)
  const float* cen  = (const float*)d_in[1];  // (2048,784)
  const float* ls   = (const float*)d_in[2];  // (2048,)
  const float* W    = (const float*)d_in[3];  // (10,2048)
  const float* bias = (const float*)d_in[4];  // (10,)
  float* out = (float*)d_out;                 // (16384,10)

  unsigned char* ws = (unsigned char*)d_ws;
  unsigned short* xb  = (unsigned short*)(ws);              // 16384*832*2 = 27,262,976
  unsigned short* cbp = (unsigned short*)(ws + 27262976);   //  2048*832*2 =  3,407,872
  unsigned short* wb  = (unsigned short*)(ws + 30670848);   //   16*2048*2 =     65,536
  float* x2 = (float*)(ws + 30736384);                      // 16384*4
  float* c2 = (float*)(ws + 30801920);                      //  2048*4
  float* sc = (float*)(ws + 30810112);                      //  2048*4   (end 30,818,304)

  prep_rows<<<B_ROWS / 4, 256, 0, stream>>>(x, xb, x2);
  prep_cpack<<<(NKC * NCG) / 4, 256, 0, stream>>>(cen, cbp);
  prep_csq<<<C_DIM / 4, 256, 0, stream>>>(cen, c2);
  prep_misc<<<(B_ROWS * NOUT + 16 * C_DIM + C_DIM + 255) / 256, 256, 0, stream>>>(
      ls, W, bias, sc, wb, out);
  rbf_main<<<dim3(B_ROWS / 128, C_DIM / 128), 256, 0, stream>>>(
      (const __bf16*)xb, (const bf16x8*)cbp, (const __bf16*)wb, x2, c2, sc, out);
}

// Round 4
// 170.077 us; speedup vs baseline: 1.0036x; 1.0036x over previous
//
#include <hip/hip_runtime.h>

// RBF classifier: out = exp(-(||x-c||^2) * exp(-2*log_sigma)) @ W^T + b
// B=16384, D=784, C=2048, OUT=10. All fp32 in/out.
//
// R4: single-barrier software-pipelined K-loop. A: LDS double-buffered 8KB
// stage via global_load_lds (source-side XOR swizzle). B: packed MFMA frags
// loaded global->VGPR one full iteration ahead (fixes R3's exposed L2
// latency). Barrier vmcnt drain overlaps compute. K pad 784->832.

#define B_ROWS 16384
#define D_DIM  784
#define C_DIM  2048
#define NOUT   10
#define KPAD   832            // 26 x 32
#define NKC    26             // k-chunks of 32
#define NCG    128            // col-groups of 16
#define LOG2E  1.4426950408889634f

typedef __attribute__((ext_vector_type(8))) __bf16 bf16x8;
typedef __attribute__((ext_vector_type(4))) float  f32x4;
typedef __attribute__((ext_vector_type(4))) unsigned short ushort4v;

__device__ __forceinline__ unsigned short f2bf(float f) {
  union { float f; unsigned int u; } v; v.f = f;
  unsigned int u = v.u;
  return (unsigned short)((u + 0x7fffu + ((u >> 16) & 1u)) >> 16);  // RNE
}

// async global->LDS, 16B per lane. LDS dest = wave-uniform base + lane*16.
__device__ __forceinline__ void async16(const __bf16* g, const __bf16* l) {
  __builtin_amdgcn_global_load_lds((const __attribute__((address_space(1))) void*)g,
                                   (__attribute__((address_space(3))) void*)l,
                                   16, 0, 0);
}

// --- x prep: fp32 row -> bf16 row (padded to KPAD zeros) + sum of squares.
__global__ __launch_bounds__(256) void prep_rows(const float* __restrict__ src,
                                                 unsigned short* __restrict__ dst,
                                                 float* __restrict__ sq) {
  const int row  = blockIdx.x * 4 + (threadIdx.x >> 6);
  const int lane = threadIdx.x & 63;
  const float* s = src + (size_t)row * D_DIM;
  unsigned short* d = dst + (size_t)row * KPAD;
  float acc = 0.f;
#pragma unroll
  for (int c = 0; c < 4; ++c) {
    const int ch = lane + c * 64;           // ushort4 chunk index, 208 total
    if (ch < 196) {
      const float4 v = ((const float4*)s)[ch];
      ushort4v o; o.x = f2bf(v.x); o.y = f2bf(v.y); o.z = f2bf(v.z); o.w = f2bf(v.w);
      *(ushort4v*)(d + ch * 4) = o;
      acc += v.x * v.x + v.y * v.y + v.z * v.z + v.w * v.w;
    } else if (ch < 208) {
      ushort4v z = {0, 0, 0, 0};
      *(ushort4v*)(d + ch * 4) = z;
    }
  }
#pragma unroll
  for (int off = 32; off > 0; off >>= 1) acc += __shfl_down(acc, off);
  if (lane == 0) sq[row] = acc;
}

// centres -> packed MFMA B-fragments. tile t = kc*NCG+cg; lane (q,l16) holds
// B[k=kc*32+q*8+j][n=cg*16+l16], j=0..7 (16B per lane). Coalesced write.
__global__ __launch_bounds__(256) void prep_cpack(const float* __restrict__ cen,
                                                  unsigned short* __restrict__ dst) {
  const int tile = blockIdx.x * 4 + (threadIdx.x >> 6);   // 0..NKC*NCG-1
  const int lane = threadIdx.x & 63;
  const int kc = tile >> 7;
  const int cg = tile & 127;
  const int c  = cg * 16 + (lane & 15);
  const int k  = kc * 32 + (lane >> 4) * 8;
  ushort4v o0 = {0, 0, 0, 0}, o1 = {0, 0, 0, 0};
  if (k + 8 <= D_DIM) {  // 784 % 8 == 0: chunks fully in or fully pad
    const float4 v0 = *(const float4*)(cen + (size_t)c * D_DIM + k);
    const float4 v1 = *(const float4*)(cen + (size_t)c * D_DIM + k + 4);
    o0.x = f2bf(v0.x); o0.y = f2bf(v0.y); o0.z = f2bf(v0.z); o0.w = f2bf(v0.w);
    o1.x = f2bf(v1.x); o1.y = f2bf(v1.y); o1.z = f2bf(v1.z); o1.w = f2bf(v1.w);
  }
  unsigned short* p = dst + ((size_t)tile * 64 + lane) * 8;
  *(ushort4v*)p = o0;
  *(ushort4v*)(p + 4) = o1;
}

// centre squared norms (wave per row).
__global__ __launch_bounds__(256) void prep_csq(const float* __restrict__ cen,
                                                float* __restrict__ sq) {
  const int row  = blockIdx.x * 4 + (threadIdx.x >> 6);
  const int lane = threadIdx.x & 63;
  const float* s = cen + (size_t)row * D_DIM;
  float acc = 0.f;
#pragma unroll
  for (int c = 0; c < 4; ++c) {
    const int ch = lane + c * 64;
    if (ch < 196) {
      const float4 v = ((const float4*)s)[ch];
      acc += v.x * v.x + v.y * v.y + v.z * v.z + v.w * v.w;
    }
  }
#pragma unroll
  for (int off = 32; off > 0; off >>= 1) acc += __shfl_down(acc, off);
  if (lane == 0) sq[row] = acc;
}

// fused tiny preps: out=bias | Wb bf16 (16,2048; rows 10..15 zero) | scale
// (pre-multiplied by log2(e) so epilogue uses exp2).
__global__ __launch_bounds__(256) void prep_misc(const float* __restrict__ ls,
                                                 const float* __restrict__ W,
                                                 const float* __restrict__ bias,
                                                 float* __restrict__ scale,
                                                 unsigned short* __restrict__ wb,
                                                 float* __restrict__ out) {
  const int i = blockIdx.x * 256 + threadIdx.x;
  if (i < B_ROWS * NOUT) out[i] = bias[i % NOUT];
  const int j = i - B_ROWS * NOUT;
  if (j >= 0 && j < 16 * C_DIM)
    wb[j] = ((j >> 11) < NOUT) ? f2bf(W[(j >> 11) * C_DIM + (j & 2047)]) : (unsigned short)0;
  const int k = j - 16 * C_DIM;
  if (k >= 0 && k < C_DIM) scale[k] = __expf(-2.f * ls[k]) * LOG2E;
}

// --- main: 128x128 tile, BK=32, 4 waves 2x2, single barrier per K-iter.
// A LDS dbuf (2x8KB) overlaid by Ph(34KB) in epilogue; B direct from L2,
// prefetched one iter ahead.
__global__ __launch_bounds__(256, 4) void rbf_main(
    const __bf16* __restrict__ xb, const bf16x8* __restrict__ cbp,
    const __bf16* __restrict__ wb,
    const float* __restrict__ x2, const float* __restrict__ c2,
    const float* __restrict__ scale, float* __restrict__ out) {
  __shared__ char smem[34816];               // max(16KB A dbuf, 34816B Ph)
  __bf16* As = (__bf16*)smem;                // 2 bufs x 4096 shorts
  __bf16* Ph = (__bf16*)smem;                // 128 x 136 (epilogue overlay)
  __shared__ float x2s[128], c2s[128], scs[128];

  const int tid  = threadIdx.x;
  const int w    = tid >> 6;
  const int lane = tid & 63;
  const int q    = lane >> 4;
  const int l16  = lane & 15;
  const int brow = blockIdx.x * 128;
  const int bcol = blockIdx.y * 128;

  if (tid < 128) x2s[tid] = x2[brow + tid];
  else { c2s[tid - 128] = c2[bcol + tid - 128]; scs[tid - 128] = scale[bcol + tid - 128]; }

  // A staging map (source-side XOR swizzle; LDS written strictly in lane
  // order as global_load_lds requires). Issue r covers rows r*64..r*64+63.
  // LDS slot (row, chunk=(tid&3)) <- global chunk (tid&3)^(row&3).
  const int srow = tid >> 2;                       // 0..63
  const int scg  = (tid & 3) ^ (srow & 3);
  const __bf16* gA = xb + (size_t)(brow + srow) * KPAD + scg * 8;
  const __bf16* lAw = As + w * 512;                // + buf*4096 + r*2048

  const int wr = (w >> 1) * 64;       // wave row offset
  const int wc = (w & 1) * 64;        // wave col offset
  const bf16x8* cbw = cbp + ((size_t)((bcol >> 4) + (w & 1) * 4)) * 64 + lane;

  f32x4 acc[4][4] = {};

  // prologue: stage kc=0 into buf0; prefetch B frags kc=0.
#pragma unroll
  for (int r = 0; r < 2; ++r)
    async16(gA + (size_t)r * 64 * KPAD, lAw + r * 2048);
  bf16x8 bcur[4], bnxt[4];
#pragma unroll
  for (int j = 0; j < 4; ++j) bcur[j] = cbw[j * 64];

#pragma unroll 2
  for (int it = 0; it < NKC; ++it) {
    __syncthreads();  // drains stage(it) + B(it) — both issued a full iter ago
    const int itn = (it + 1 < NKC) ? it + 1 : NKC - 1;
    const __bf16* lAn = lAw + ((it + 1) & 1) * 4096;
#pragma unroll
    for (int r = 0; r < 2; ++r)
      async16(gA + (size_t)r * 64 * KPAD + itn * 32, lAn + r * 2048);
#pragma unroll
    for (int j = 0; j < 4; ++j) bnxt[j] = cbw[((size_t)itn * NCG + j) * 64];

    const __bf16* bufc = As + (it & 1) * 4096;
    bf16x8 af[4];
#pragma unroll
    for (int i = 0; i < 4; ++i)
      af[i] = *(const bf16x8*)&bufc[(wr + i * 16 + l16) * 32 + ((q ^ (l16 & 3)) << 3)];
#pragma unroll
    for (int i = 0; i < 4; ++i)
#pragma unroll
      for (int j = 0; j < 4; ++j)
        acc[i][j] = __builtin_amdgcn_mfma_f32_16x16x32_bf16(af[i], bcur[j], acc[i][j], 0, 0, 0);
#pragma unroll
    for (int j = 0; j < 4; ++j) bcur[j] = bnxt[j];
  }
  __syncthreads();  // all waves done with As before Ph overlay

  // epilogue 1: d2 -> phi -> Ph (bf16). C/D layout: col=lane&15, row=q*4+r.
#pragma unroll
  for (int i = 0; i < 4; ++i) {
    float xv[4];
#pragma unroll
    for (int r = 0; r < 4; ++r) xv[r] = x2s[wr + i * 16 + q * 4 + r];
#pragma unroll
    for (int j = 0; j < 4; ++j) {
      const int cl = wc + j * 16 + l16;
      const float c2v = c2s[cl];
      const float sc = scs[cl];   // includes log2(e)
#pragma unroll
      for (int r = 0; r < 4; ++r) {
        const int rl = wr + i * 16 + q * 4 + r;
        const float d2 = fmaxf(fmaf(-2.f, acc[i][j][r], xv[r] + c2v), 0.f);
        Ph[rl * 136 + cl] = (__bf16)__builtin_exp2f(-d2 * sc);
      }
    }
  }
  __syncthreads();

  // epilogue 2: out_tile(128x10) = Ph(128x128) @ Wb(16-row slice)^T, K=128.
  f32x4 oacc[2] = {};
#pragma unroll
  for (int kk = 0; kk < 4; ++kk) {
    const bf16x8 bw = *(const bf16x8*)&wb[(size_t)l16 * C_DIM + bcol + kk * 32 + q * 8];
#pragma unroll
    for (int mi = 0; mi < 2; ++mi) {
      const bf16x8 ap = *(const bf16x8*)&Ph[(w * 32 + mi * 16 + l16) * 136 + kk * 32 + q * 8];
      oacc[mi] = __builtin_amdgcn_mfma_f32_16x16x32_bf16(ap, bw, oacc[mi], 0, 0, 0);
    }
  }
  if (l16 < NOUT) {
#pragma unroll
    for (int mi = 0; mi < 2; ++mi)
#pragma unroll
      for (int r = 0; r < 4; ++r) {
        const int grow = brow + w * 32 + mi * 16 + q * 4 + r;
        atomicAdd(&out[grow * NOUT + l16], oacc[mi][r]);
      }
  }
}

extern "C" void kernel_launch(void* const* d_in, const int* in_sizes, int n_in,
                              void* d_out, int out_size, void* d_ws, size_t ws_size,
                              hipStream_t stream) {
  const float* x    = (const float*)d_in[0];  // (16384,784)
  const float* cen  = (const float*)d_in[1];  // (2048,784)
  const float* ls   = (const float*)d_in[2];  // (2048,)
  const float* W    = (const float*)d_in[3];  // (10,2048)
  const float* bias = (const float*)d_in[4];  // (10,)
  float* out = (float*)d_out;                 // (16384,10)

  unsigned char* ws = (unsigned char*)d_ws;
  unsigned short* xb  = (unsigned short*)(ws);              // 16384*832*2 = 27,262,976
  unsigned short* cbp = (unsigned short*)(ws + 27262976);   //  2048*832*2 =  3,407,872
  unsigned short* wb  = (unsigned short*)(ws + 30670848);   //   16*2048*2 =     65,536
  float* x2 = (float*)(ws + 30736384);                      // 16384*4
  float* c2 = (float*)(ws + 30801920);                      //  2048*4
  float* sc = (float*)(ws + 30810112);                      //  2048*4   (end 30,818,304)

  prep_rows<<<B_ROWS / 4, 256, 0, stream>>>(x, xb, x2);
  prep_cpack<<<(NKC * NCG) / 4, 256, 0, stream>>>(cen, cbp);
  prep_csq<<<C_DIM / 4, 256, 0, stream>>>(cen, c2);
  prep_misc<<<(B_ROWS * NOUT + 16 * C_DIM + C_DIM + 255) / 256, 256, 0, stream>>>(
      ls, W, bias, sc, wb, out);
  rbf_main<<<dim3(B_ROWS / 128, C_DIM / 128), 256, 0, stream>>>(
      (const __bf16*)xb, (const bf16x8*)cbp, (const __bf16*)wb, x2, c2, sc, out);
}